// Round 3
// baseline (688.849 us; speedup 1.0000x reference)
//
#include <hip/hip_runtime.h>

#define BKT_SHIFT 8            // 256 nodes per bucket
#define NSUB 8                 // sub-cursors per bucket (XCD-affine via blockIdx%8)
#define SCOL_CAP 12288         // LDS col staging per bucket (48 KB); mean bucket = 6400

// ---- two-level CSR build ------------------------------------------------

// Per-(bucket,sub) histogram. sub is a pure function of the edge index so the
// bin pass (256 edges/block) sees a constant sub per block == blockIdx%8,
// which matches the default round-robin block->XCD dispatch.
__global__ void hist8(const int* __restrict__ dst, int* __restrict__ bcnt8, int E) {
    int e = blockIdx.x * blockDim.x + threadIdx.x;
    if (e < E) {
        int idx = (dst[e] >> BKT_SHIFT) * NSUB + ((e >> 8) & (NSUB - 1));
        atomicAdd(&bcnt8[idx], 1);
    }
}

// Single block, 1024 threads: exclusive scan of M (<=4096) ints; out[M] = E.
__global__ void scan_small(const int* __restrict__ in, int* __restrict__ out, int M, int E) {
    __shared__ int lds[1024];
    int t = threadIdx.x;
    int base = t * 4;
    int v0 = (base + 0 < M) ? in[base + 0] : 0;
    int v1 = (base + 1 < M) ? in[base + 1] : 0;
    int v2 = (base + 2 < M) ? in[base + 2] : 0;
    int v3 = (base + 3 < M) ? in[base + 3] : 0;
    lds[t] = v0 + v1 + v2 + v3;
    __syncthreads();
    for (int off = 1; off < 1024; off <<= 1) {
        int add = (t >= off) ? lds[t - off] : 0;
        __syncthreads();
        lds[t] += add;
        __syncthreads();
    }
    int p = (t == 0) ? 0 : lds[t - 1];
    if (base + 0 < M) out[base + 0] = p;  p += v0;
    if (base + 1 < M) out[base + 1] = p;  p += v1;
    if (base + 2 < M) out[base + 2] = p;  p += v2;
    if (base + 3 < M) out[base + 3] = p;
    if (t == 0) out[M] = E;
}

// Append (dl<<24)|src into the edge's (bucket,sub) segment. One block = 256
// consecutive edges => one sub => one XCD writes each segment (L2-local fills).
__global__ void bin_kernel(const int* __restrict__ src, const int* __restrict__ dst,
                           const int* __restrict__ bbase8, int* __restrict__ bcur8,
                           int* __restrict__ staged, int E) {
    int e = blockIdx.x * 256 + threadIdx.x;
    if (e < E) {
        int d = dst[e], s = src[e];
        int idx = (d >> BKT_SHIFT) * NSUB + ((e >> 8) & (NSUB - 1));
        int p = bbase8[idx] + atomicAdd(&bcur8[idx], 1);
        staged[p] = ((d & 255) << 24) | s;   // src < 2^24
    }
}

// One block per bucket: LDS count -> scan (writes rp!) -> LDS place -> coalesced col flush.
__global__ void fine_fill(const int* __restrict__ staged, const int* __restrict__ bbase8,
                          int* __restrict__ rp, int* __restrict__ col,
                          int N, int E, int NBKT) {
    __shared__ int scnt[256];
    __shared__ int srel[256];
    __shared__ int scur[256];
    __shared__ int scol[SCOL_CAP];
    int b = blockIdx.x, t = threadIdx.x;
    int n0 = b << BKT_SHIFT;
    int nn = min(256, N - n0);
    int e0 = bbase8[b * NSUB];
    int e1 = (b + 1 < NBKT) ? bbase8[(b + 1) * NSUB] : E;
    int m = e1 - e0;

    scnt[t] = 0; scur[t] = 0;
    __syncthreads();
    for (int i = t; i < m; i += 256) {
        int dl = ((unsigned)staged[e0 + i]) >> 24;
        atomicAdd(&scnt[dl], 1);
    }
    __syncthreads();
    int inc_in = scnt[t];
    for (int off = 1; off < 256; off <<= 1) {   // Hillis-Steele inclusive
        int add = (t >= off) ? scnt[t - off] : 0;
        __syncthreads();
        scnt[t] += add;
        __syncthreads();
    }
    int excl = scnt[t] - inc_in;                // exclusive prefix
    srel[t] = excl;
    if (t < nn) rp[n0 + t] = e0 + excl;
    if (b == NBKT - 1 && t == 0) rp[N] = E;
    __syncthreads();

    if (m <= SCOL_CAP) {
        for (int i = t; i < m; i += 256) {
            int v = staged[e0 + i];
            int dl = ((unsigned)v) >> 24;
            int p = srel[dl] + atomicAdd(&scur[dl], 1);
            scol[p] = v & 0xFFFFFF;
        }
        __syncthreads();
        for (int i = t; i < m; i += 256) col[e0 + i] = scol[i];
    } else {  // statistically unreachable overflow fallback
        for (int i = t; i < m; i += 256) {
            int v = staged[e0 + i];
            int dl = ((unsigned)v) >> 24;
            int p = srel[dl] + atomicAdd(&scur[dl], 1);
            col[e0 + p] = v & 0xFFFFFF;
        }
    }
}

// ---- Fused aggregate + MLP ---------------------------------------------
// Block = 256 threads = 8 nodes x 32 channels; 8-way unrolled neighbor gather
// for MLP (R2: VALUBusy 5% -> latency-bound fix), MLP through LDS.

template <bool RELU_OUT>
__global__ void agg_mlp(const float* __restrict__ xin, const int* __restrict__ rp,
                        const int* __restrict__ col,
                        const float* __restrict__ Wa, const float* __restrict__ ba,
                        const float* __restrict__ Wb, const float* __restrict__ bb,
                        float* __restrict__ out, int N) {
    __shared__ float sWa[32 * 16];
    __shared__ float sWb[16 * 32];
    __shared__ float sba[16], sbb[32];
    __shared__ float sv[8][32];
    __shared__ float st1[8][16];

    int t = threadIdx.x;
    sWa[t] = Wa[t];  sWa[t + 256] = Wa[t + 256];
    sWb[t] = Wb[t];  sWb[t + 256] = Wb[t + 256];
    if (t < 16) sba[t] = ba[t];
    if (t < 32) sbb[t] = bb[t];

    int ln = t >> 5;
    int c  = t & 31;
    int n  = blockIdx.x * 8 + ln;
    bool act = (n < N);

    if (act) {
        float v = xin[(size_t)n * 32 + c];
        int ks = rp[n], ke = rp[n + 1];
        int k = ks;
        for (; k + 8 <= ke; k += 8) {
            int s0 = col[k + 0], s1 = col[k + 1], s2 = col[k + 2], s3 = col[k + 3];
            int s4 = col[k + 4], s5 = col[k + 5], s6 = col[k + 6], s7 = col[k + 7];
            float a0 = xin[(size_t)s0 * 32 + c];
            float a1 = xin[(size_t)s1 * 32 + c];
            float a2 = xin[(size_t)s2 * 32 + c];
            float a3 = xin[(size_t)s3 * 32 + c];
            float a4 = xin[(size_t)s4 * 32 + c];
            float a5 = xin[(size_t)s5 * 32 + c];
            float a6 = xin[(size_t)s6 * 32 + c];
            float a7 = xin[(size_t)s7 * 32 + c];
            v += ((a0 + a1) + (a2 + a3)) + ((a4 + a5) + (a6 + a7));
        }
        for (; k < ke; ++k) v += xin[(size_t)col[k] * 32 + c];
        sv[ln][c] = v;
    }
    __syncthreads();

    if (act && c < 16) {
        float tacc = sba[c];
        #pragma unroll
        for (int cc = 0; cc < 32; ++cc) tacc += sv[ln][cc] * sWa[cc * 16 + c];
        st1[ln][c] = fmaxf(tacc, 0.f);
    }
    __syncthreads();

    if (act) {
        float acc = sbb[c];
        #pragma unroll
        for (int j = 0; j < 16; ++j) acc += st1[ln][j] * sWb[j * 32 + c];
        out[(size_t)n * 32 + c] = RELU_OUT ? fmaxf(acc, 0.f) : acc;
    }
}

// ---- Launch -------------------------------------------------------------

extern "C" void kernel_launch(void* const* d_in, const int* in_sizes, int n_in,
                              void* d_out, int out_size, void* d_ws, size_t ws_size,
                              hipStream_t stream) {
    const float* x  = (const float*)d_in[0];
    const int*   ei = (const int*)d_in[1];
    const float* W1 = (const float*)d_in[2];
    const float* b1 = (const float*)d_in[3];
    const float* W2 = (const float*)d_in[4];
    const float* b2 = (const float*)d_in[5];
    const float* W3 = (const float*)d_in[6];
    const float* b3 = (const float*)d_in[7];
    const float* W4 = (const float*)d_in[8];
    const float* b4 = (const float*)d_in[9];

    const int N = in_sizes[0] / 32;
    const int E = in_sizes[1] / 2;
    const int* src = ei;
    const int* dst = ei + E;

    const int NBKT = (N + 255) >> BKT_SHIFT;
    const int M = NBKT * NSUB;

    char* ws = (char*)d_ws;
    size_t o = 0;
    auto alloc = [&](size_t bytes) -> char* {
        o = (o + 255) & ~(size_t)255;
        char* r = ws + o;
        o += bytes;
        return r;
    };
    int*   bcnt8  = (int*)  alloc(4 * (size_t)M);
    int*   bbase8 = (int*)  alloc(4 * (size_t)(M + 1));
    int*   bcur8  = (int*)  alloc(4 * (size_t)M);
    int*   staged = (int*)  alloc(4 * (size_t)E);
    int*   rp     = (int*)  alloc(4 * (size_t)(N + 1));
    int*   col    = (int*)  alloc(4 * (size_t)E);
    float* h      = (float*)alloc(4 * (size_t)N * 32);

    hipMemsetAsync(bcnt8, 0, 4 * (size_t)M, stream);
    hipMemsetAsync(bcur8, 0, 4 * (size_t)M, stream);

    hist8<<<(E + 255) / 256, 256, 0, stream>>>(dst, bcnt8, E);
    scan_small<<<1, 1024, 0, stream>>>(bcnt8, bbase8, M, E);
    bin_kernel<<<(E + 255) / 256, 256, 0, stream>>>(src, dst, bbase8, bcur8, staged, E);
    fine_fill<<<NBKT, 256, 0, stream>>>(staged, bbase8, rp, col, N, E, NBKT);

    agg_mlp<true ><<<(N + 7) / 8, 256, 0, stream>>>(x, rp, col, W1, b1, W2, b2, h, N);
    agg_mlp<false><<<(N + 7) / 8, 256, 0, stream>>>(h, rp, col, W3, b3, W4, b4,
                                                    (float*)d_out, N);
}